// Round 1
// baseline (1287.612 us; speedup 1.0000x reference)
//
#include <hip/hip_runtime.h>
#include <math.h>

#define NI 1024
#define NJ 1024
#define NC 128
#define NH 8
#define ND 32

// ---------------------------------------------------------------- layernorm
__global__ __launch_bounds__(64) void ln_kernel(const float* __restrict__ x1,
                                                const float* __restrict__ x2,
                                                const float* __restrict__ w,
                                                const float* __restrict__ b,
                                                float* __restrict__ x1n,
                                                float* __restrict__ x2n) {
    int row = blockIdx.x;
    const float* src;
    float* dst;
    if (row < NI) { src = x1 + row * NC; dst = x1n + row * NC; }
    else          { src = x2 + (row - NI) * NC; dst = x2n + (row - NI) * NC; }
    int t = threadIdx.x;
    float a = src[t], c = src[t + 64];
    float s = a + c;
#pragma unroll
    for (int m = 1; m < 64; m <<= 1) s += __shfl_xor(s, m);
    float mean = s * (1.0f / 128.0f);
    float da = a - mean, dc = c - mean;
    float v = da * da + dc * dc;
#pragma unroll
    for (int m = 1; m < 64; m <<= 1) v += __shfl_xor(v, m);
    float rs = rsqrtf(v * (1.0f / 128.0f) + 1e-5f);
    dst[t]      = da * rs * w[t] + b[t];
    dst[t + 64] = dc * rs * w[t + 64] + b[t + 64];
}

// ------------------------------------------------- tri_bias + mask bias
// bias[h][i][j] = sum_c x_pair[i][j][c]*wb[h][c] + 1e9*(mask[i][j]-1)
// 32 lanes per (i,j) row; 8 rows per 256-thread block.
__global__ __launch_bounds__(256) void bias_kernel(const float4* __restrict__ xp,
                                                   const float4* __restrict__ wb,
                                                   const float* __restrict__ mask,
                                                   float* __restrict__ bias) {
    int t = threadIdx.x;
    int lane = t & 31;
    long ij = (long)blockIdx.x * 8 + (t >> 5);
    float4 x = xp[ij * 32 + lane];
    float acc[8];
#pragma unroll
    for (int h = 0; h < 8; h++) {
        float4 wv = wb[h * 32 + lane];
        acc[h] = x.x * wv.x + x.y * wv.y + x.z * wv.z + x.w * wv.w;
    }
    // split-butterfly reduction across the 32-lane group (9 shuffles total)
    int p = lane & 1;
#pragma unroll
    for (int k = 0; k < 4; k++) {
        float send = p ? acc[k] : acc[4 + k];
        float recv = __shfl_xor(send, 1);
        float keep = p ? acc[4 + k] : acc[k];
        acc[k] = keep + recv;
    }
    int q2 = (lane >> 1) & 1;
#pragma unroll
    for (int k = 0; k < 2; k++) {
        float send = q2 ? acc[k] : acc[2 + k];
        float recv = __shfl_xor(send, 2);
        float keep = q2 ? acc[2 + k] : acc[k];
        acc[k] = keep + recv;
    }
    int r4 = (lane >> 2) & 1;
    {
        float send = r4 ? acc[0] : acc[1];
        float recv = __shfl_xor(send, 4);
        float keep = r4 ? acc[1] : acc[0];
        acc[0] = keep + recv;
    }
    acc[0] += __shfl_xor(acc[0], 8);
    acc[0] += __shfl_xor(acc[0], 16);
    if (lane < 8) {
        int h = 4 * (lane & 1) + 2 * ((lane >> 1) & 1) + ((lane >> 2) & 1);
        float mb = 1e9f * (mask[ij] - 1.0f);
        bias[(long)h * (NI * NJ) + ij] = acc[0] + mb;
    }
}

// --------------------------------------- fused Q/K/V/G projection (GEMM-NT)
// Y[1024][256]x4; seg0=Q(*1/sqrt(D)) from xq, seg1=K,seg2=V from xkv, seg3=G=sigmoid(.+bg) from xq
__global__ __launch_bounds__(64) void proj_kernel(const float4* __restrict__ xq,
                                                  const float4* __restrict__ xkv,
                                                  const float4* __restrict__ wq,
                                                  const float4* __restrict__ wk,
                                                  const float4* __restrict__ wv,
                                                  const float4* __restrict__ wg,
                                                  const float* __restrict__ bg,
                                                  float* __restrict__ Qb,
                                                  float* __restrict__ Kb,
                                                  float* __restrict__ Vb,
                                                  float* __restrict__ Gb) {
    __shared__ float Xs[32 * 132];
    __shared__ float Ws[32 * 132];
    int t = threadIdx.x;
    int m0 = blockIdx.y * 32;
    int nt = blockIdx.x;        // 0..31
    int seg = nt >> 3;          // 0..3
    int nbase = (nt & 7) * 32;  // within-seg col base
    const float4* X = (seg == 0 || seg == 3) ? xq : xkv;
    const float4* W = (seg == 0) ? wq : (seg == 1) ? wk : (seg == 2) ? wv : wg;
#pragma unroll
    for (int i = 0; i < 16; i++) {
        int f = t + 64 * i;
        int r = f >> 5, c4 = f & 31;
        *(float4*)&Xs[r * 132 + c4 * 4] = X[(m0 + r) * 32 + c4];
        *(float4*)&Ws[r * 132 + c4 * 4] = W[(nbase + r) * 32 + c4];
    }
    __syncthreads();
    int tn = t & 7, tm = t >> 3;
    float acc[4][4] = {};
#pragma unroll
    for (int k0 = 0; k0 < 128; k0 += 4) {
        float xa[4][4], wa[4][4];
#pragma unroll
        for (int u = 0; u < 4; u++) {
            float4 xv = *(const float4*)&Xs[(tm * 4 + u) * 132 + k0];
            xa[u][0] = xv.x; xa[u][1] = xv.y; xa[u][2] = xv.z; xa[u][3] = xv.w;
        }
#pragma unroll
        for (int v = 0; v < 4; v++) {
            float4 wv2 = *(const float4*)&Ws[(tn * 4 + v) * 132 + k0];
            wa[v][0] = wv2.x; wa[v][1] = wv2.y; wa[v][2] = wv2.z; wa[v][3] = wv2.w;
        }
#pragma unroll
        for (int u = 0; u < 4; u++)
#pragma unroll
            for (int v = 0; v < 4; v++)
#pragma unroll
                for (int w = 0; w < 4; w++) acc[u][v] += xa[u][w] * wa[v][w];
    }
    float* out = (seg == 0) ? Qb : (seg == 1) ? Kb : (seg == 2) ? Vb : Gb;
#pragma unroll
    for (int u = 0; u < 4; u++) {
        int row = m0 + tm * 4 + u;
#pragma unroll
        for (int v = 0; v < 4; v++) {
            int col = nbase + tn * 4 + v;
            float val = acc[u][v];
            if (seg == 0) val *= 0.17677669529663687f;  // 1/sqrt(32)
            if (seg == 3) val = 1.0f / (1.0f + expf(-(val + bg[col])));
            out[row * 256 + col] = val;
        }
    }
}

// --------------------------- S[h][q][j] = Q[q]·K[j] + bias (opt transposed)
__global__ __launch_bounds__(256) void bmm_s_kernel(const float* __restrict__ Q,
                                                    const float* __restrict__ K,
                                                    const float* __restrict__ bias,
                                                    float* __restrict__ S,
                                                    int transB) {
    __shared__ float Qs[64 * 36];
    __shared__ float Kst[32 * 68];  // transposed: Kst[d][j]
    int t = threadIdx.x;
    int h = blockIdx.z;
    int q0 = blockIdx.y * 64, j0 = blockIdx.x * 64;
#pragma unroll
    for (int i = 0; i < 8; i++) {
        int f = t + 256 * i;
        int r = f >> 5, d = f & 31;
        Qs[r * 36 + d] = Q[(q0 + r) * 256 + h * 32 + d];
        Kst[d * 68 + r] = K[(j0 + r) * 256 + h * 32 + d];
    }
    __syncthreads();
    int jg = t & 15, qg = t >> 4;
    float acc[4][4] = {};
#pragma unroll
    for (int d0 = 0; d0 < 32; d0 += 4) {
        float qa[4][4], ka[4][4];
#pragma unroll
        for (int u = 0; u < 4; u++) {
            float4 x = *(const float4*)&Qs[(qg * 4 + u) * 36 + d0];
            qa[u][0] = x.x; qa[u][1] = x.y; qa[u][2] = x.z; qa[u][3] = x.w;
        }
#pragma unroll
        for (int w = 0; w < 4; w++) {
            float4 x = *(const float4*)&Kst[(d0 + w) * 68 + jg * 4];
            ka[w][0] = x.x; ka[w][1] = x.y; ka[w][2] = x.z; ka[w][3] = x.w;
        }
#pragma unroll
        for (int u = 0; u < 4; u++)
#pragma unroll
            for (int v = 0; v < 4; v++)
#pragma unroll
                for (int w = 0; w < 4; w++) acc[u][v] += qa[u][w] * ka[w][v];
    }
#pragma unroll
    for (int u = 0; u < 4; u++) {
        int qq = q0 + qg * 4 + u;
#pragma unroll
        for (int v = 0; v < 4; v++) {
            int jj = j0 + jg * 4 + v;
            long bidx = transB ? ((long)(h * 1024 + jj) * 1024 + qq)
                               : ((long)(h * 1024 + qq) * 1024 + jj);
            S[(long)(h * 1024 + qq) * 1024 + jj] = acc[u][v] + bias[bidx];
        }
    }
}

// ------------------------------------------------ softmax rows (in place)
__global__ __launch_bounds__(64) void softmax_kernel(float* __restrict__ S) {
    long row = blockIdx.x;
    float4* p = (float4*)(S + row * 1024);
    int t = threadIdx.x;
    float4 v[4];
    float mx = -1e30f;
#pragma unroll
    for (int c = 0; c < 4; c++) {
        v[c] = p[c * 64 + t];
        mx = fmaxf(mx, fmaxf(fmaxf(v[c].x, v[c].y), fmaxf(v[c].z, v[c].w)));
    }
#pragma unroll
    for (int m = 1; m < 64; m <<= 1) mx = fmaxf(mx, __shfl_xor(mx, m));
    float sum = 0.f;
#pragma unroll
    for (int c = 0; c < 4; c++) {
        v[c].x = expf(v[c].x - mx); v[c].y = expf(v[c].y - mx);
        v[c].z = expf(v[c].z - mx); v[c].w = expf(v[c].w - mx);
        sum += v[c].x + v[c].y + v[c].z + v[c].w;
    }
#pragma unroll
    for (int m = 1; m < 64; m <<= 1) sum += __shfl_xor(sum, m);
    float inv = 1.0f / sum;
#pragma unroll
    for (int c = 0; c < 4; c++) {
        v[c].x *= inv; v[c].y *= inv; v[c].z *= inv; v[c].w *= inv;
        p[c * 64 + t] = v[c];
    }
}

// --------------- O[q][h*32+d] += sum_{j in chunk} P[h][q][j] * V[j][h*32+d]
// grid (js=4, qt=8, h=8); P is normalized so j-splits sum linearly via atomics.
__global__ __launch_bounds__(256) void bmm_o_kernel(const float* __restrict__ P,
                                                    const float* __restrict__ V,
                                                    float* __restrict__ O) {
    __shared__ float Ps[128 * 68];
    __shared__ float Vs[64 * 36];
    int t = threadIdx.x;
    int h = blockIdx.z;
    int q0 = blockIdx.y * 128;
    int jbase = blockIdx.x * 256;
    int qg = t >> 3, dg = t & 7;  // 32 q-groups x 8 d-groups
    float4 acc[4] = {};
    for (int cc = 0; cc < 4; cc++) {
        int j0 = jbase + cc * 64;
        __syncthreads();
#pragma unroll
        for (int i = 0; i < 32; i++) {
            int f = t + 256 * i;
            int r = f >> 6, j = f & 63;
            Ps[r * 68 + j] = P[(long)(h * 1024 + q0 + r) * 1024 + j0 + j];
        }
#pragma unroll
        for (int i = 0; i < 8; i++) {
            int f = t + 256 * i;
            int r = f >> 5, d = f & 31;
            Vs[r * 36 + d] = V[(j0 + r) * 256 + h * 32 + d];
        }
        __syncthreads();
#pragma unroll
        for (int jj = 0; jj < 64; jj += 4) {
            float pa[4][4];
            float4 vv[4];
#pragma unroll
            for (int u = 0; u < 4; u++) {
                float4 x = *(const float4*)&Ps[(qg * 4 + u) * 68 + jj];
                pa[u][0] = x.x; pa[u][1] = x.y; pa[u][2] = x.z; pa[u][3] = x.w;
            }
#pragma unroll
            for (int w = 0; w < 4; w++) vv[w] = *(const float4*)&Vs[(jj + w) * 36 + dg * 4];
#pragma unroll
            for (int u = 0; u < 4; u++)
#pragma unroll
                for (int w = 0; w < 4; w++) {
                    acc[u].x += pa[u][w] * vv[w].x;
                    acc[u].y += pa[u][w] * vv[w].y;
                    acc[u].z += pa[u][w] * vv[w].z;
                    acc[u].w += pa[u][w] * vv[w].w;
                }
        }
    }
#pragma unroll
    for (int u = 0; u < 4; u++) {
        int row = q0 + qg * 4 + u;
        float* op = &O[row * 256 + h * 32 + dg * 4];
        atomicAdd(op + 0, acc[u].x);
        atomicAdd(op + 1, acc[u].y);
        atomicAdd(op + 2, acc[u].z);
        atomicAdd(op + 3, acc[u].w);
    }
}

// ------------- Y = (O*G) @ wo^T + bo + resid  -> ws copy + d_out segment
__global__ __launch_bounds__(64) void outproj_kernel(const float4* __restrict__ O,
                                                     const float4* __restrict__ G,
                                                     const float4* __restrict__ wo,
                                                     const float* __restrict__ bo,
                                                     const float* __restrict__ resid,
                                                     float* __restrict__ y_ws,
                                                     float* __restrict__ y_out) {
    __shared__ float Xs[32 * 260];
    __shared__ float Ws[32 * 260];
    int t = threadIdx.x;
    int m0 = blockIdx.y * 32, n0 = blockIdx.x * 32;
#pragma unroll
    for (int i = 0; i < 32; i++) {
        int f = t + 64 * i;
        int r = f >> 6, c4 = f & 63;
        float4 ov = O[(m0 + r) * 64 + c4];
        float4 gv = G[(m0 + r) * 64 + c4];
        ov.x *= gv.x; ov.y *= gv.y; ov.z *= gv.z; ov.w *= gv.w;
        *(float4*)&Xs[r * 260 + c4 * 4] = ov;
        *(float4*)&Ws[r * 260 + c4 * 4] = wo[(n0 + r) * 64 + c4];
    }
    __syncthreads();
    int tn = t & 7, tm = t >> 3;
    float acc[4][4] = {};
#pragma unroll
    for (int k0 = 0; k0 < 256; k0 += 4) {
        float xa[4][4], wa[4][4];
#pragma unroll
        for (int u = 0; u < 4; u++) {
            float4 x = *(const float4*)&Xs[(tm * 4 + u) * 260 + k0];
            xa[u][0] = x.x; xa[u][1] = x.y; xa[u][2] = x.z; xa[u][3] = x.w;
        }
#pragma unroll
        for (int v = 0; v < 4; v++) {
            float4 x = *(const float4*)&Ws[(tn * 4 + v) * 260 + k0];
            wa[v][0] = x.x; wa[v][1] = x.y; wa[v][2] = x.z; wa[v][3] = x.w;
        }
#pragma unroll
        for (int u = 0; u < 4; u++)
#pragma unroll
            for (int v = 0; v < 4; v++)
#pragma unroll
                for (int w = 0; w < 4; w++) acc[u][v] += xa[u][w] * wa[v][w];
    }
#pragma unroll
    for (int u = 0; u < 4; u++) {
        int row = m0 + tm * 4 + u;
#pragma unroll
        for (int v = 0; v < 4; v++) {
            int col = n0 + tn * 4 + v;
            float val = acc[u][v] + bo[col] + resid[row * 128 + col];
            y_ws[row * 128 + col] = val;
            y_out[row * 128 + col] = val;
        }
    }
}

extern "C" void kernel_launch(void* const* d_in, const int* in_sizes, int n_in,
                              void* d_out, int out_size, void* d_ws, size_t ws_size,
                              hipStream_t stream) {
    const float* x1     = (const float*)d_in[0];
    const float* x2     = (const float*)d_in[1];
    const float* x_pair = (const float*)d_in[2];
    const float* mask   = (const float*)d_in[3];
    const float* ln_w   = (const float*)d_in[4];
    const float* ln_b   = (const float*)d_in[5];
    const float* wb     = (const float*)d_in[6];
    const float* wq1 = (const float*)d_in[7],  *wk1 = (const float*)d_in[8],
               * wv1 = (const float*)d_in[9],  *wg1 = (const float*)d_in[10],
               * bg1 = (const float*)d_in[11], *wo1 = (const float*)d_in[12],
               * bo1 = (const float*)d_in[13];
    const float* wq2 = (const float*)d_in[14], *wk2 = (const float*)d_in[15],
               * wv2 = (const float*)d_in[16], *wg2 = (const float*)d_in[17],
               * bg2 = (const float*)d_in[18], *wo2 = (const float*)d_in[19],
               * bo2 = (const float*)d_in[20];
    float* out = (float*)d_out;

    float* ws   = (float*)d_ws;
    float* x1n  = ws;                 // 131072
    float* x2n  = ws + 131072;        // 131072
    float* x1u  = ws + 262144;        // 131072
    float* x2u  = ws + 393216;        // 131072 (scratch)
    float* Qb   = ws + 524288;        // 262144
    float* Kb   = ws + 786432;        // 262144
    float* Vb   = ws + 1048576;       // 262144
    float* Gb   = ws + 1310720;       // 262144
    float* Ob   = ws + 1572864;       // 262144
    float* Bias = ws + 1835008;       // 8388608
    float* Sb   = ws + 10223616;      // 8388608  (total ~74.5 MB)

    ln_kernel<<<2048, 64, 0, stream>>>(x1, x2, ln_w, ln_b, x1n, x2n);
    bias_kernel<<<131072, 256, 0, stream>>>((const float4*)x_pair, (const float4*)wb, mask, Bias);

    // ---- MHA 1: Q from x1n, K/V from x2n
    proj_kernel<<<dim3(32, 32), 64, 0, stream>>>((const float4*)x1n, (const float4*)x2n,
                                                 (const float4*)wq1, (const float4*)wk1,
                                                 (const float4*)wv1, (const float4*)wg1,
                                                 bg1, Qb, Kb, Vb, Gb);
    bmm_s_kernel<<<dim3(16, 16, 8), 256, 0, stream>>>(Qb, Kb, Bias, Sb, 0);
    softmax_kernel<<<8192, 64, 0, stream>>>(Sb);
    hipMemsetAsync(Ob, 0, 262144 * sizeof(float), stream);
    bmm_o_kernel<<<dim3(4, 8, 8), 256, 0, stream>>>(Sb, Vb, Ob);
    outproj_kernel<<<dim3(4, 32), 64, 0, stream>>>((const float4*)Ob, (const float4*)Gb,
                                                   (const float4*)wo1, bo1, x1n, x1u, out);

    // ---- MHA 2: Q from x2n, K/V from x1u, bias transposed
    proj_kernel<<<dim3(32, 32), 64, 0, stream>>>((const float4*)x2n, (const float4*)x1u,
                                                 (const float4*)wq2, (const float4*)wk2,
                                                 (const float4*)wv2, (const float4*)wg2,
                                                 bg2, Qb, Kb, Vb, Gb);
    bmm_s_kernel<<<dim3(16, 16, 8), 256, 0, stream>>>(Qb, Kb, Bias, Sb, 1);
    softmax_kernel<<<8192, 64, 0, stream>>>(Sb);
    hipMemsetAsync(Ob, 0, 262144 * sizeof(float), stream);
    bmm_o_kernel<<<dim3(4, 8, 8), 256, 0, stream>>>(Sb, Vb, Ob);
    outproj_kernel<<<dim3(4, 32), 64, 0, stream>>>((const float4*)Ob, (const float4*)Gb,
                                                   (const float4*)wo2, bo2, x2n, x2u, out + 131072);
}

// Round 2
// 1197.055 us; speedup vs baseline: 1.0756x; 1.0756x over previous
//
#include <hip/hip_runtime.h>
#include <math.h>

#define NI 1024
#define NJ 1024
#define NC 128
#define NH 8
#define ND 32

// ---------------------------------------------------------------- layernorm
__global__ __launch_bounds__(64) void ln_kernel(const float* __restrict__ x1,
                                                const float* __restrict__ x2,
                                                const float* __restrict__ w,
                                                const float* __restrict__ b,
                                                float* __restrict__ x1n,
                                                float* __restrict__ x2n) {
    int row = blockIdx.x;
    const float* src;
    float* dst;
    if (row < NI) { src = x1 + row * NC; dst = x1n + row * NC; }
    else          { src = x2 + (row - NI) * NC; dst = x2n + (row - NI) * NC; }
    int t = threadIdx.x;
    float a = src[t], c = src[t + 64];
    float s = a + c;
#pragma unroll
    for (int m = 1; m < 64; m <<= 1) s += __shfl_xor(s, m);
    float mean = s * (1.0f / 128.0f);
    float da = a - mean, dc = c - mean;
    float v = da * da + dc * dc;
#pragma unroll
    for (int m = 1; m < 64; m <<= 1) v += __shfl_xor(v, m);
    float rs = rsqrtf(v * (1.0f / 128.0f) + 1e-5f);
    dst[t]      = da * rs * w[t] + b[t];
    dst[t + 64] = dc * rs * w[t + 64] + b[t + 64];
}

// ------------------------------------------------- tri_bias + mask bias
__global__ __launch_bounds__(256) void bias_kernel(const float4* __restrict__ xp,
                                                   const float4* __restrict__ wb,
                                                   const float* __restrict__ mask,
                                                   float* __restrict__ bias) {
    int t = threadIdx.x;
    int lane = t & 31;
    long ij = (long)blockIdx.x * 8 + (t >> 5);
    float4 x = xp[ij * 32 + lane];
    float acc[8];
#pragma unroll
    for (int h = 0; h < 8; h++) {
        float4 wv = wb[h * 32 + lane];
        acc[h] = x.x * wv.x + x.y * wv.y + x.z * wv.z + x.w * wv.w;
    }
    int p = lane & 1;
#pragma unroll
    for (int k = 0; k < 4; k++) {
        float send = p ? acc[k] : acc[4 + k];
        float recv = __shfl_xor(send, 1);
        float keep = p ? acc[4 + k] : acc[k];
        acc[k] = keep + recv;
    }
    int q2 = (lane >> 1) & 1;
#pragma unroll
    for (int k = 0; k < 2; k++) {
        float send = q2 ? acc[k] : acc[2 + k];
        float recv = __shfl_xor(send, 2);
        float keep = q2 ? acc[2 + k] : acc[k];
        acc[k] = keep + recv;
    }
    int r4 = (lane >> 2) & 1;
    {
        float send = r4 ? acc[0] : acc[1];
        float recv = __shfl_xor(send, 4);
        float keep = r4 ? acc[1] : acc[0];
        acc[0] = keep + recv;
    }
    acc[0] += __shfl_xor(acc[0], 8);
    acc[0] += __shfl_xor(acc[0], 16);
    if (lane < 8) {
        int h = 4 * (lane & 1) + 2 * ((lane >> 1) & 1) + ((lane >> 2) & 1);
        float mb = 1e9f * (mask[ij] - 1.0f);
        bias[(long)h * (NI * NJ) + ij] = acc[0] + mb;
    }
}

// --------------------------------------- fused Q/K/V/G projection (GEMM-NT)
__global__ __launch_bounds__(64) void proj_kernel(const float4* __restrict__ xq,
                                                  const float4* __restrict__ xkv,
                                                  const float4* __restrict__ wq,
                                                  const float4* __restrict__ wk,
                                                  const float4* __restrict__ wv,
                                                  const float4* __restrict__ wg,
                                                  const float* __restrict__ bg,
                                                  float* __restrict__ Qb,
                                                  float* __restrict__ Kb,
                                                  float* __restrict__ Vb,
                                                  float* __restrict__ Gb) {
    __shared__ float Xs[32 * 132];
    __shared__ float Ws[32 * 132];
    int t = threadIdx.x;
    int m0 = blockIdx.y * 32;
    int nt = blockIdx.x;
    int seg = nt >> 3;
    int nbase = (nt & 7) * 32;
    const float4* X = (seg == 0 || seg == 3) ? xq : xkv;
    const float4* W = (seg == 0) ? wq : (seg == 1) ? wk : (seg == 2) ? wv : wg;
#pragma unroll
    for (int i = 0; i < 16; i++) {
        int f = t + 64 * i;
        int r = f >> 5, c4 = f & 31;
        *(float4*)&Xs[r * 132 + c4 * 4] = X[(m0 + r) * 32 + c4];
        *(float4*)&Ws[r * 132 + c4 * 4] = W[(nbase + r) * 32 + c4];
    }
    __syncthreads();
    int tn = t & 7, tm = t >> 3;
    float acc[4][4] = {};
#pragma unroll
    for (int k0 = 0; k0 < 128; k0 += 4) {
        float xa[4][4], wa[4][4];
#pragma unroll
        for (int u = 0; u < 4; u++) {
            float4 xv = *(const float4*)&Xs[(tm * 4 + u) * 132 + k0];
            xa[u][0] = xv.x; xa[u][1] = xv.y; xa[u][2] = xv.z; xa[u][3] = xv.w;
        }
#pragma unroll
        for (int v = 0; v < 4; v++) {
            float4 wv2 = *(const float4*)&Ws[(tn * 4 + v) * 132 + k0];
            wa[v][0] = wv2.x; wa[v][1] = wv2.y; wa[v][2] = wv2.z; wa[v][3] = wv2.w;
        }
#pragma unroll
        for (int u = 0; u < 4; u++)
#pragma unroll
            for (int v = 0; v < 4; v++)
#pragma unroll
                for (int w = 0; w < 4; w++) acc[u][v] += xa[u][w] * wa[v][w];
    }
    float* out = (seg == 0) ? Qb : (seg == 1) ? Kb : (seg == 2) ? Vb : Gb;
#pragma unroll
    for (int u = 0; u < 4; u++) {
        int row = m0 + tm * 4 + u;
#pragma unroll
        for (int v = 0; v < 4; v++) {
            int col = nbase + tn * 4 + v;
            float val = acc[u][v];
            if (seg == 0) val *= 0.17677669529663687f;  // 1/sqrt(32)
            if (seg == 3) val = 1.0f / (1.0f + expf(-(val + bg[col])));
            out[row * 256 + col] = val;
        }
    }
}

// ------------------------------------------------------ flash attention
// grid (js=2, qt=16, h=8), 512 threads. Tq=64 rows of q, j-half of 512 keys
// per block, iterated in 8 tiles of 64. Bias[h][i][j]: transB=0 reads rows=q;
// transB=1 reads rows=key (LDS transpose at staging). Outputs unnormalized
// O-numerator + (m,l) per row; combine_kernel merges the two j-halves.
__global__ __launch_bounds__(512) void flash_kernel(const float* __restrict__ Q,
                                                    const float* __restrict__ K,
                                                    const float* __restrict__ V,
                                                    const float* __restrict__ Bias,
                                                    float* __restrict__ Opart,
                                                    float* __restrict__ Ml,
                                                    int transB) {
    __shared__ float Qs[64 * 40];   // Q tile; reused as O-combine buffer
    __shared__ float Kst[32 * 68];  // K transposed [d][j]
    __shared__ float Vs[64 * 40];   // V tile [j][d]
    __shared__ float Bs[64 * 68];   // bias tile [q][j]; reused as P
    __shared__ float alpha_s[64];
    __shared__ float l_s[64];
    __shared__ float m_s[64];
    int t = threadIdx.x;
    int js = blockIdx.x;
    int q0 = blockIdx.y * 64;
    int h  = blockIdx.z;
    // S-phase identity: 32 row-groups (2 q each) x 16 lanes (4 j each)
    int qg = t >> 4, jg = t & 15;
    // PV-phase identity: 2 j-chunks x 32 row-groups (2 q) x 8 d-groups (4 d)
    int jc = t >> 8, u2 = t & 255, qg2 = u2 >> 3, dg = u2 & 7;
    const float4* Q4 = (const float4*)Q;
    const float4* K4 = (const float4*)K;
    const float4* V4 = (const float4*)V;
    const float4* B4 = (const float4*)Bias;
    {
        int r = t >> 3, d4 = t & 7;
        *(float4*)&Qs[r * 40 + d4 * 4] = Q4[(q0 + r) * 64 + h * 8 + d4];
    }
    float m_old[2] = {-3e38f, -3e38f};
    float l[2] = {0.f, 0.f};
    float4 oacc[2];
    oacc[0] = make_float4(0.f, 0.f, 0.f, 0.f);
    oacc[1] = make_float4(0.f, 0.f, 0.f, 0.f);
    for (int tile = 0; tile < 8; tile++) {
        int j0 = js * 512 + tile * 64;
        __syncthreads();
        // ---- stage K (transposed) and V
        {
            int r = t >> 3, d4 = t & 7;
            float4 kv = K4[(j0 + r) * 64 + h * 8 + d4];
            float4 vv = V4[(j0 + r) * 64 + h * 8 + d4];
            Kst[(d4 * 4 + 0) * 68 + r] = kv.x;
            Kst[(d4 * 4 + 1) * 68 + r] = kv.y;
            Kst[(d4 * 4 + 2) * 68 + r] = kv.z;
            Kst[(d4 * 4 + 3) * 68 + r] = kv.w;
            *(float4*)&Vs[r * 40 + d4 * 4] = vv;
        }
        // ---- stage bias tile into Bs[q][j]
        if (!transB) {
#pragma unroll
            for (int i = 0; i < 2; i++) {
                int f = t + 512 * i;
                int r = f >> 4, c4 = f & 15;
                float4 bv = B4[((long)h * 1024 + q0 + r) * 256 + (j0 >> 2) + c4];
                *(float4*)&Bs[r * 68 + c4 * 4] = bv;
            }
        } else {
#pragma unroll
            for (int i = 0; i < 2; i++) {
                int f = t + 512 * i;
                int r = f >> 4, c4 = f & 15;  // r = key row, c4 = q quad
                float4 bv = B4[((long)h * 1024 + j0 + r) * 256 + (q0 >> 2) + c4];
                Bs[(c4 * 4 + 0) * 68 + r] = bv.x;
                Bs[(c4 * 4 + 1) * 68 + r] = bv.y;
                Bs[(c4 * 4 + 2) * 68 + r] = bv.z;
                Bs[(c4 * 4 + 3) * 68 + r] = bv.w;
            }
        }
        __syncthreads();
        // ---- S = Q K^T + bias (per-thread 2x4)
        float4 acc4[2];
        acc4[0] = make_float4(0.f, 0.f, 0.f, 0.f);
        acc4[1] = make_float4(0.f, 0.f, 0.f, 0.f);
#pragma unroll
        for (int d0 = 0; d0 < 32; d0 += 4) {
            float4 qa[2], ka[4];
            qa[0] = *(const float4*)&Qs[(qg * 2 + 0) * 40 + d0];
            qa[1] = *(const float4*)&Qs[(qg * 2 + 1) * 40 + d0];
#pragma unroll
            for (int w = 0; w < 4; w++)
                ka[w] = *(const float4*)&Kst[(d0 + w) * 68 + jg * 4];
#pragma unroll
            for (int u = 0; u < 2; u++) {
                const float* qp = (const float*)&qa[u];
#pragma unroll
                for (int w = 0; w < 4; w++) {
                    float qw = qp[w];
                    acc4[u].x += qw * ka[w].x;
                    acc4[u].y += qw * ka[w].y;
                    acc4[u].z += qw * ka[w].z;
                    acc4[u].w += qw * ka[w].w;
                }
            }
        }
        float al_loc[2];
#pragma unroll
        for (int u = 0; u < 2; u++) {
            float4 bv = *(const float4*)&Bs[(qg * 2 + u) * 68 + jg * 4];
            acc4[u].x += bv.x; acc4[u].y += bv.y;
            acc4[u].z += bv.z; acc4[u].w += bv.w;
            // ---- online softmax
            float mx = fmaxf(fmaxf(acc4[u].x, acc4[u].y), fmaxf(acc4[u].z, acc4[u].w));
#pragma unroll
            for (int m = 1; m < 16; m <<= 1) mx = fmaxf(mx, __shfl_xor(mx, m));
            float mn = fmaxf(m_old[u], mx);
            float al = expf(m_old[u] - mn);
            float4 p;
            p.x = expf(acc4[u].x - mn);
            p.y = expf(acc4[u].y - mn);
            p.z = expf(acc4[u].z - mn);
            p.w = expf(acc4[u].w - mn);
            float rs = p.x + p.y + p.z + p.w;
#pragma unroll
            for (int m = 1; m < 16; m <<= 1) rs += __shfl_xor(rs, m);
            l[u] = l[u] * al + rs;
            m_old[u] = mn;
            al_loc[u] = al;
            *(float4*)&Bs[(qg * 2 + u) * 68 + jg * 4] = p;  // own 2x4 slot
        }
        if (jg == 0) {
            alpha_s[qg * 2 + 0] = al_loc[0];
            alpha_s[qg * 2 + 1] = al_loc[1];
        }
        __syncthreads();
        // ---- O = O*alpha + P V  (thread covers its jc half of 64 keys)
        float a0 = alpha_s[qg2 * 2 + 0], a1 = alpha_s[qg2 * 2 + 1];
        oacc[0].x *= a0; oacc[0].y *= a0; oacc[0].z *= a0; oacc[0].w *= a0;
        oacc[1].x *= a1; oacc[1].y *= a1; oacc[1].z *= a1; oacc[1].w *= a1;
        int jb = jc * 32;
#pragma unroll
        for (int jj = 0; jj < 32; jj += 4) {
            float4 pa[2], vv[4];
            pa[0] = *(const float4*)&Bs[(qg2 * 2 + 0) * 68 + jb + jj];
            pa[1] = *(const float4*)&Bs[(qg2 * 2 + 1) * 68 + jb + jj];
#pragma unroll
            for (int w = 0; w < 4; w++)
                vv[w] = *(const float4*)&Vs[(jb + jj + w) * 40 + dg * 4];
#pragma unroll
            for (int u = 0; u < 2; u++) {
                const float* pp = (const float*)&pa[u];
#pragma unroll
                for (int w = 0; w < 4; w++) {
                    float pw = pp[w];
                    oacc[u].x += pw * vv[w].x;
                    oacc[u].y += pw * vv[w].y;
                    oacc[u].z += pw * vv[w].z;
                    oacc[u].w += pw * vv[w].w;
                }
            }
        }
    }
    __syncthreads();
    // ---- write m,l; combine the two jc partials via LDS (reuse Qs)
    if (jg == 0) {
        l_s[qg * 2 + 0] = l[0];  l_s[qg * 2 + 1] = l[1];
        m_s[qg * 2 + 0] = m_old[0]; m_s[qg * 2 + 1] = m_old[1];
    }
    if (jc == 0) {
        *(float4*)&Qs[(qg2 * 2 + 0) * 40 + dg * 4] = oacc[0];
        *(float4*)&Qs[(qg2 * 2 + 1) * 40 + dg * 4] = oacc[1];
    }
    __syncthreads();
    if (jc == 1) {
#pragma unroll
        for (int u = 0; u < 2; u++) {
            float4 s = *(float4*)&Qs[(qg2 * 2 + u) * 40 + dg * 4];
            s.x += oacc[u].x; s.y += oacc[u].y; s.z += oacc[u].z; s.w += oacc[u].w;
            *(float4*)&Qs[(qg2 * 2 + u) * 40 + dg * 4] = s;
        }
    }
    __syncthreads();
    {
        int r = t >> 3, d4 = t & 7;
        float4 ov = *(float4*)&Qs[r * 40 + d4 * 4];
        ((float4*)Opart)[((long)(js * 8 + h) * 1024 + q0 + r) * 8 + d4] = ov;
    }
    if (t < 64) {
        Ml[((js * 2 + 0) * 8 + h) * 1024 + q0 + t] = m_s[t];
        Ml[((js * 2 + 1) * 8 + h) * 1024 + q0 + t] = l_s[t];
    }
}

// --------------------- merge j-half partials: O = sum(w_i * O_i) / sum(w_i*l_i)
__global__ __launch_bounds__(256) void combine_kernel(const float4* __restrict__ Opart,
                                                      const float* __restrict__ Ml,
                                                      float4* __restrict__ Ob) {
    int gid = blockIdx.x * 256 + threadIdx.x;  // 65536 total
    int h = gid >> 13, q = (gid >> 3) & 1023, d4 = gid & 7;
    float m0 = Ml[(0 * 8 + h) * 1024 + q];
    float l0 = Ml[(1 * 8 + h) * 1024 + q];
    float m1 = Ml[(2 * 8 + h) * 1024 + q];
    float l1 = Ml[(3 * 8 + h) * 1024 + q];
    float M = fmaxf(m0, m1);
    float w0 = expf(m0 - M), w1 = expf(m1 - M);
    float inv = 1.0f / (l0 * w0 + l1 * w1);
    float4 o0 = Opart[((long)(0 * 8 + h) * 1024 + q) * 8 + d4];
    float4 o1 = Opart[((long)(1 * 8 + h) * 1024 + q) * 8 + d4];
    float4 r;
    r.x = (o0.x * w0 + o1.x * w1) * inv;
    r.y = (o0.y * w0 + o1.y * w1) * inv;
    r.z = (o0.z * w0 + o1.z * w1) * inv;
    r.w = (o0.w * w0 + o1.w * w1) * inv;
    Ob[q * 64 + h * 8 + d4] = r;
}

// ------------- Y = (O*G) @ wo^T + bo + resid  -> ws copy + d_out segment
__global__ __launch_bounds__(64) void outproj_kernel(const float4* __restrict__ O,
                                                     const float4* __restrict__ G,
                                                     const float4* __restrict__ wo,
                                                     const float* __restrict__ bo,
                                                     const float* __restrict__ resid,
                                                     float* __restrict__ y_ws,
                                                     float* __restrict__ y_out) {
    __shared__ float Xs[32 * 260];
    __shared__ float Ws[32 * 260];
    int t = threadIdx.x;
    int m0 = blockIdx.y * 32, n0 = blockIdx.x * 32;
#pragma unroll
    for (int i = 0; i < 32; i++) {
        int f = t + 64 * i;
        int r = f >> 6, c4 = f & 63;
        float4 ov = O[(m0 + r) * 64 + c4];
        float4 gv = G[(m0 + r) * 64 + c4];
        ov.x *= gv.x; ov.y *= gv.y; ov.z *= gv.z; ov.w *= gv.w;
        *(float4*)&Xs[r * 260 + c4 * 4] = ov;
        *(float4*)&Ws[r * 260 + c4 * 4] = wo[(n0 + r) * 64 + c4];
    }
    __syncthreads();
    int tn = t & 7, tm = t >> 3;
    float acc[4][4] = {};
#pragma unroll
    for (int k0 = 0; k0 < 256; k0 += 4) {
        float xa[4][4], wa[4][4];
#pragma unroll
        for (int u = 0; u < 4; u++) {
            float4 x = *(const float4*)&Xs[(tm * 4 + u) * 260 + k0];
            xa[u][0] = x.x; xa[u][1] = x.y; xa[u][2] = x.z; xa[u][3] = x.w;
        }
#pragma unroll
        for (int v = 0; v < 4; v++) {
            float4 x = *(const float4*)&Ws[(tn * 4 + v) * 260 + k0];
            wa[v][0] = x.x; wa[v][1] = x.y; wa[v][2] = x.z; wa[v][3] = x.w;
        }
#pragma unroll
        for (int u = 0; u < 4; u++)
#pragma unroll
            for (int v = 0; v < 4; v++)
#pragma unroll
                for (int w = 0; w < 4; w++) acc[u][v] += xa[u][w] * wa[v][w];
    }
#pragma unroll
    for (int u = 0; u < 4; u++) {
        int row = m0 + tm * 4 + u;
#pragma unroll
        for (int v = 0; v < 4; v++) {
            int col = n0 + tn * 4 + v;
            float val = acc[u][v] + bo[col] + resid[row * 128 + col];
            y_ws[row * 128 + col] = val;
            y_out[row * 128 + col] = val;
        }
    }
}

extern "C" void kernel_launch(void* const* d_in, const int* in_sizes, int n_in,
                              void* d_out, int out_size, void* d_ws, size_t ws_size,
                              hipStream_t stream) {
    const float* x1     = (const float*)d_in[0];
    const float* x2     = (const float*)d_in[1];
    const float* x_pair = (const float*)d_in[2];
    const float* mask   = (const float*)d_in[3];
    const float* ln_w   = (const float*)d_in[4];
    const float* ln_b   = (const float*)d_in[5];
    const float* wb     = (const float*)d_in[6];
    const float* wq1 = (const float*)d_in[7],  *wk1 = (const float*)d_in[8],
               * wv1 = (const float*)d_in[9],  *wg1 = (const float*)d_in[10],
               * bg1 = (const float*)d_in[11], *wo1 = (const float*)d_in[12],
               * bo1 = (const float*)d_in[13];
    const float* wq2 = (const float*)d_in[14], *wk2 = (const float*)d_in[15],
               * wv2 = (const float*)d_in[16], *wg2 = (const float*)d_in[17],
               * bg2 = (const float*)d_in[18], *wo2 = (const float*)d_in[19],
               * bo2 = (const float*)d_in[20];
    float* out = (float*)d_out;

    float* ws    = (float*)d_ws;
    float* x1n   = ws;                 // 131072
    float* x2n   = ws + 131072;        // 131072
    float* x1u   = ws + 262144;        // 131072
    float* x2u   = ws + 393216;        // 131072 (scratch)
    float* Qb    = ws + 524288;        // 262144
    float* Kb    = ws + 786432;        // 262144
    float* Vb    = ws + 1048576;       // 262144
    float* Gb    = ws + 1310720;       // 262144
    float* Ob    = ws + 1572864;       // 262144
    float* Bias  = ws + 1835008;       // 8388608
    float* Opart = ws + 10223616;      // 524288
    float* Mlb   = ws + 10747904;      // 32768

    ln_kernel<<<2048, 64, 0, stream>>>(x1, x2, ln_w, ln_b, x1n, x2n);
    bias_kernel<<<131072, 256, 0, stream>>>((const float4*)x_pair, (const float4*)wb, mask, Bias);

    // ---- MHA 1: Q from x1n, K/V from x2n
    proj_kernel<<<dim3(32, 32), 64, 0, stream>>>((const float4*)x1n, (const float4*)x2n,
                                                 (const float4*)wq1, (const float4*)wk1,
                                                 (const float4*)wv1, (const float4*)wg1,
                                                 bg1, Qb, Kb, Vb, Gb);
    flash_kernel<<<dim3(2, 16, 8), 512, 0, stream>>>(Qb, Kb, Vb, Bias, Opart, Mlb, 0);
    combine_kernel<<<256, 256, 0, stream>>>((const float4*)Opart, Mlb, (float4*)Ob);
    outproj_kernel<<<dim3(4, 32), 64, 0, stream>>>((const float4*)Ob, (const float4*)Gb,
                                                   (const float4*)wo1, bo1, x1n, x1u, out);

    // ---- MHA 2: Q from x2n, K/V from x1u, bias transposed
    proj_kernel<<<dim3(32, 32), 64, 0, stream>>>((const float4*)x2n, (const float4*)x1u,
                                                 (const float4*)wq2, (const float4*)wk2,
                                                 (const float4*)wv2, (const float4*)wg2,
                                                 bg2, Qb, Kb, Vb, Gb);
    flash_kernel<<<dim3(2, 16, 8), 512, 0, stream>>>(Qb, Kb, Vb, Bias, Opart, Mlb, 1);
    combine_kernel<<<256, 256, 0, stream>>>((const float4*)Opart, Mlb, (float4*)Ob);
    outproj_kernel<<<dim3(4, 32), 64, 0, stream>>>((const float4*)Ob, (const float4*)Gb,
                                                   (const float4*)wo2, bo2, x2n, x2u, out + 131072);
}